// Round 1
// baseline (236.456 us; speedup 1.0000x reference)
//
#include <hip/hip_runtime.h>
#include <math.h>

// ComplexEMA: y[b,d,t] = Re(sum_n gam_dn * h_dn[t]) + omega_d * x[b,d,t]
//             h[t] = q*h[t-1] + p*x[t]  (diagonal complex recurrence)
// Substitution u = h/p:  u' = q*u + x,  h = p*u, gam' = p*gam.
// 3-pass chunked scan (exact): C=32 chunks of CH=128 over L=4096.

constexpr int kD = 2048, kN = 16, kB = 2, kL = 4096;
constexpr int kC = 32;             // chunks per (b,d) row
constexpr int kCH = kL / kC;       // 128
constexpr int kDN = kD * kN;
constexpr float kSCALE = 0.25f;    // sqrt(1/N)

typedef float v2 __attribute__((ext_vector_type(2)));

static __device__ __forceinline__ v2 mkv2(float a, float b) {
    v2 r; r.x = a; r.y = b; return r;
}

static __device__ __forceinline__ v2 v2fma(v2 a, v2 b, v2 c) {
#if __has_builtin(__builtin_elementwise_fma)
    return __builtin_elementwise_fma(a, b, c);
#else
    v2 r;
    r.x = __builtin_fmaf(a.x, b.x, c.x);
    r.y = __builtin_fmaf(a.y, b.y, c.y);
    return r;
#endif
}

// ws layout (floats):
//   [0*kDN)      qr        [1*kDN) qi
//   [2*kDN)      gr = p*SCALE*gamma0     [3*kDN) gi = -p*SCALE*gamma1
//   [4*kDN)      p
//   [5*kDN)      F/Hinit buffer: kB*kD*kC*kN*2 floats (16 MB)

__global__ void coeff_kernel(const float* __restrict__ alpha,
                             const float* __restrict__ delta,
                             const float* __restrict__ theta,
                             const float* __restrict__ gamma,
                             float* __restrict__ ws) {
    int i = blockIdx.x * 256 + threadIdx.x;      // d*N + n
    if (i >= kDN) return;
    int d = i >> 4, n = i & 15;
    float p  = 1.0f / (1.0f + expf(-alpha[i]));
    float dd = 1.0f / (1.0f + expf(-delta[i]));
    float th = 1.0f / (1.0f + expf(-theta[d]));
    float phi = (float)(n + 1) * th * 0.39269908169872414f;  // 2*pi/16
    float r = 1.0f - p * dd;
    float s, c;
    sincosf(phi, &s, &c);
    ws[i]           = r * c;                         // qr
    ws[kDN + i]     = r * s;                         // qi
    ws[2 * kDN + i] = p * kSCALE * gamma[2 * i];     // gr
    ws[3 * kDN + i] = -(p * kSCALE * gamma[2 * i + 1]); // gi
    ws[4 * kDN + i] = p;
}

// Pass 1: local chunk recurrence from zero init; write end-state F.
__global__ __launch_bounds__(256) void pass1_kernel(const float* __restrict__ x,
                                                    const float* __restrict__ ws,
                                                    float* __restrict__ F) {
    int tid = blockIdx.x * 256 + threadIdx.x;    // (b*kD + d)*kC + c
    int c   = tid & (kC - 1);
    int row = tid >> 5;                          // b*kD + d
    int d   = row & (kD - 1);

    const float4* q4r = (const float4*)(ws + (size_t)d * kN);
    const float4* q4i = (const float4*)(ws + kDN + (size_t)d * kN);
    float qrA[kN], qiA[kN];
#pragma unroll
    for (int k = 0; k < 4; k++) {
        float4 t0 = q4r[k];
        qrA[4*k+0]=t0.x; qrA[4*k+1]=t0.y; qrA[4*k+2]=t0.z; qrA[4*k+3]=t0.w;
        float4 t1 = q4i[k];
        qiA[4*k+0]=t1.x; qiA[4*k+1]=t1.y; qiA[4*k+2]=t1.z; qiA[4*k+3]=t1.w;
    }
    v2 qx[kN], qy[kN], u[kN];
#pragma unroll
    for (int n = 0; n < kN; n++) {
        qx[n] = mkv2(qrA[n], qrA[n]);
        qy[n] = mkv2(-qiA[n], qiA[n]);
        u[n]  = mkv2(0.0f, 0.0f);
    }

    const float4* xp = (const float4*)(x + (size_t)row * kL + (size_t)c * kCH);
    float4 xq = xp[0];
#pragma unroll 1
    for (int i = 0; i < kCH / 4; i++) {
        int i2 = (i + 1 < kCH / 4) ? i + 1 : i;
        float4 xn = xp[i2];                       // prefetch
        float xs4[4] = {xq.x, xq.y, xq.z, xq.w};
#pragma unroll
        for (int j = 0; j < 4; j++) {
            v2 xv = mkv2(xs4[j], 0.0f);
#pragma unroll
            for (int n = 0; n < kN; n++) {
                v2 a = v2fma(qx[n], u[n], xv);
                u[n] = v2fma(qy[n], mkv2(u[n].y, u[n].x), a);
            }
        }
        xq = xn;
    }

    float4* Fp = (float4*)(F + (size_t)tid * (kN * 2));
#pragma unroll
    for (int n = 0; n < kN; n += 2)
        Fp[n >> 1] = make_float4(u[n].x, u[n].y, u[n + 1].x, u[n + 1].y);
}

// Pass 2: sequential combine over chunks per (b,d,n); write Hinit in place + h_out.
__global__ void pass2_kernel(const float* __restrict__ ws,
                             float* __restrict__ FH,
                             float* __restrict__ hout) {
    int i = blockIdx.x * 256 + threadIdx.x;      // (b*kD + d)*kN + n
    if (i >= kB * kD * kN) return;
    int n = i & 15;
    int row = i >> 4;                            // b*kD + d
    int d = row & (kD - 1);
    int dn = d * kN + n;
    float qr = ws[dn], qi = ws[kDN + dn], p = ws[4 * kDN + dn];
    // qC = q^kCH by repeated squaring (kCH = 128 = 2^7)
    float ar = qr, ai = qi;
#pragma unroll
    for (int k = 0; k < 7; k++) {
        float nr = ar * ar - ai * ai;
        float ni = 2.0f * ar * ai;
        ar = nr; ai = ni;
    }
    float Hr = 0.0f, Hi = 0.0f;
    float* base = FH + (size_t)row * kC * kN * 2;
#pragma unroll 1
    for (int c = 0; c < kC; c++) {
        size_t off = ((size_t)c * kN + n) * 2;
        float Fr = base[off], Fi = base[off + 1];
        base[off] = Hr; base[off + 1] = Hi;      // state entering chunk c
        float nHr = __builtin_fmaf(ar, Hr, __builtin_fmaf(-ai, Hi, Fr));
        float nHi = __builtin_fmaf(ar, Hi, __builtin_fmaf(ai, Hr, Fi));
        Hr = nHr; Hi = nHi;
    }
    hout[2 * i]     = p * Hr;                    // h = p * u
    hout[2 * i + 1] = p * Hi;
}

// Pass 3: rerun recurrence from correct init, emit y.
__global__ __launch_bounds__(256) void pass3_kernel(const float* __restrict__ x,
                                                    const float* __restrict__ ws,
                                                    const float* __restrict__ H,
                                                    const float* __restrict__ omega,
                                                    float* __restrict__ y) {
    int tid = blockIdx.x * 256 + threadIdx.x;    // (b*kD + d)*kC + c
    int c   = tid & (kC - 1);
    int row = tid >> 5;
    int d   = row & (kD - 1);

    const float4* q4r = (const float4*)(ws + (size_t)d * kN);
    const float4* q4i = (const float4*)(ws + kDN + (size_t)d * kN);
    const float4* g4r = (const float4*)(ws + 2 * kDN + (size_t)d * kN);
    const float4* g4i = (const float4*)(ws + 3 * kDN + (size_t)d * kN);
    float qrA[kN], qiA[kN], grA[kN], giA[kN];
#pragma unroll
    for (int k = 0; k < 4; k++) {
        float4 t0 = q4r[k];
        qrA[4*k+0]=t0.x; qrA[4*k+1]=t0.y; qrA[4*k+2]=t0.z; qrA[4*k+3]=t0.w;
        float4 t1 = q4i[k];
        qiA[4*k+0]=t1.x; qiA[4*k+1]=t1.y; qiA[4*k+2]=t1.z; qiA[4*k+3]=t1.w;
        float4 t2 = g4r[k];
        grA[4*k+0]=t2.x; grA[4*k+1]=t2.y; grA[4*k+2]=t2.z; grA[4*k+3]=t2.w;
        float4 t3 = g4i[k];
        giA[4*k+0]=t3.x; giA[4*k+1]=t3.y; giA[4*k+2]=t3.z; giA[4*k+3]=t3.w;
    }
    v2 qx[kN], qy[kN], g[kN], u[kN];
#pragma unroll
    for (int n = 0; n < kN; n++) {
        qx[n] = mkv2(qrA[n], qrA[n]);
        qy[n] = mkv2(-qiA[n], qiA[n]);
        g[n]  = mkv2(grA[n], giA[n]);
    }
    const float4* Hp = (const float4*)(H + (size_t)tid * (kN * 2));
#pragma unroll
    for (int k = 0; k < kN / 2; k++) {
        float4 h = Hp[k];
        u[2 * k]     = mkv2(h.x, h.y);
        u[2 * k + 1] = mkv2(h.z, h.w);
    }
    float om = omega[d];

    const float4* xp = (const float4*)(x + (size_t)row * kL + (size_t)c * kCH);
    float4*       yp = (float4*)(y + (size_t)row * kL + (size_t)c * kCH);
    float4 xq = xp[0];
#pragma unroll 1
    for (int i = 0; i < kCH / 4; i++) {
        int i2 = (i + 1 < kCH / 4) ? i + 1 : i;
        float4 xn = xp[i2];                       // prefetch
        float xs4[4] = {xq.x, xq.y, xq.z, xq.w};
        float ys4[4];
#pragma unroll
        for (int j = 0; j < 4; j++) {
            v2 xv = mkv2(xs4[j], 0.0f);
            v2 acc0 = mkv2(0.0f, 0.0f), acc1 = mkv2(0.0f, 0.0f);
            v2 acc2 = mkv2(0.0f, 0.0f), acc3 = mkv2(0.0f, 0.0f);
#pragma unroll
            for (int n = 0; n < kN; n += 4) {
                v2 a;
                a = v2fma(qx[n], u[n], xv);
                u[n] = v2fma(qy[n], mkv2(u[n].y, u[n].x), a);
                acc0 = v2fma(g[n], u[n], acc0);
                a = v2fma(qx[n+1], u[n+1], xv);
                u[n+1] = v2fma(qy[n+1], mkv2(u[n+1].y, u[n+1].x), a);
                acc1 = v2fma(g[n+1], u[n+1], acc1);
                a = v2fma(qx[n+2], u[n+2], xv);
                u[n+2] = v2fma(qy[n+2], mkv2(u[n+2].y, u[n+2].x), a);
                acc2 = v2fma(g[n+2], u[n+2], acc2);
                a = v2fma(qx[n+3], u[n+3], xv);
                u[n+3] = v2fma(qy[n+3], mkv2(u[n+3].y, u[n+3].x), a);
                acc3 = v2fma(g[n+3], u[n+3], acc3);
            }
            v2 s = (acc0 + acc1) + (acc2 + acc3);
            ys4[j] = s.x + s.y + om * xs4[j];
        }
        yp[i] = make_float4(ys4[0], ys4[1], ys4[2], ys4[3]);
        xq = xn;
    }
}

extern "C" void kernel_launch(void* const* d_in, const int* in_sizes, int n_in,
                              void* d_out, int out_size, void* d_ws, size_t ws_size,
                              hipStream_t stream) {
    const float* x     = (const float*)d_in[0];
    const float* alpha = (const float*)d_in[1];
    const float* delta = (const float*)d_in[2];
    const float* theta = (const float*)d_in[3];
    const float* gamma = (const float*)d_in[4];
    const float* omega = (const float*)d_in[5];
    float* y    = (float*)d_out;
    float* hout = y + (size_t)kB * kD * kL;      // (B,D,N,2) after y
    float* ws   = (float*)d_ws;
    float* F    = ws + 5 * (size_t)kDN;

    coeff_kernel<<<kDN / 256, 256, 0, stream>>>(alpha, delta, theta, gamma, ws);
    pass1_kernel<<<(kB * kD * kC) / 256, 256, 0, stream>>>(x, ws, F);
    pass2_kernel<<<(kB * kD * kN) / 256, 256, 0, stream>>>(ws, F, hout);
    pass3_kernel<<<(kB * kD * kC) / 256, 256, 0, stream>>>(x, ws, F, omega, y);
}

// Round 2
// 187.296 us; speedup vs baseline: 1.2625x; 1.2625x over previous
//
#include <hip/hip_runtime.h>
#include <math.h>

// ComplexEMA: y[b,d,t] = Re(sum_n gam_dn * h_dn[t]) + omega_d * x[b,d,t]
//             h[t] = q*h[t-1] + p*x[t]  (diagonal complex recurrence)
// Substitution u = h/p:  u' = q*u + x,  h = p*u, gam' = p*gam.
// 3-pass chunked scan (exact): C=32 chunks of CH=128 over L=4096.
// R2: super-iterations of 32 steps with register-burst x loads / y stores
//     so each lane fully covers its 128B cache lines in a short window
//     (R1 showed 1.55x read / 2.85x write amplification from partial lines).

constexpr int kD = 2048, kN = 16, kB = 2, kL = 4096;
constexpr int kC = 32;             // chunks per (b,d) row
constexpr int kCH = kL / kC;       // 128
constexpr int kDN = kD * kN;
constexpr float kSCALE = 0.25f;    // sqrt(1/N)

typedef float v2 __attribute__((ext_vector_type(2)));

static __device__ __forceinline__ v2 mkv2(float a, float b) {
    v2 r; r.x = a; r.y = b; return r;
}

static __device__ __forceinline__ v2 v2fma(v2 a, v2 b, v2 c) {
#if __has_builtin(__builtin_elementwise_fma)
    return __builtin_elementwise_fma(a, b, c);
#else
    v2 r;
    r.x = __builtin_fmaf(a.x, b.x, c.x);
    r.y = __builtin_fmaf(a.y, b.y, c.y);
    return r;
#endif
}

// ws layout (floats):
//   [0*kDN)      qr        [1*kDN) qi
//   [2*kDN)      gr = p*SCALE*gamma0     [3*kDN) gi = -p*SCALE*gamma1
//   [4*kDN)      p
//   [5*kDN)      F/Hinit buffer: kB*kD*kC*kN*2 floats (16 MB)

__global__ void coeff_kernel(const float* __restrict__ alpha,
                             const float* __restrict__ delta,
                             const float* __restrict__ theta,
                             const float* __restrict__ gamma,
                             float* __restrict__ ws) {
    int i = blockIdx.x * 256 + threadIdx.x;      // d*N + n
    if (i >= kDN) return;
    int d = i >> 4, n = i & 15;
    float p  = 1.0f / (1.0f + expf(-alpha[i]));
    float dd = 1.0f / (1.0f + expf(-delta[i]));
    float th = 1.0f / (1.0f + expf(-theta[d]));
    float phi = (float)(n + 1) * th * 0.39269908169872414f;  // 2*pi/16
    float r = 1.0f - p * dd;
    float s, c;
    sincosf(phi, &s, &c);
    ws[i]           = r * c;                         // qr
    ws[kDN + i]     = r * s;                         // qi
    ws[2 * kDN + i] = p * kSCALE * gamma[2 * i];     // gr
    ws[3 * kDN + i] = -(p * kSCALE * gamma[2 * i + 1]); // gi
    ws[4 * kDN + i] = p;
}

// Pass 1: local chunk recurrence from zero init; write end-state F.
__global__ __launch_bounds__(256) void pass1_kernel(const float* __restrict__ x,
                                                    const float* __restrict__ ws,
                                                    float* __restrict__ F) {
    int tid = blockIdx.x * 256 + threadIdx.x;    // (b*kD + d)*kC + c
    int c   = tid & (kC - 1);
    int row = tid >> 5;                          // b*kD + d
    int d   = row & (kD - 1);

    const float4* q4r = (const float4*)(ws + (size_t)d * kN);
    const float4* q4i = (const float4*)(ws + kDN + (size_t)d * kN);
    float qrA[kN], qiA[kN];
#pragma unroll
    for (int k = 0; k < 4; k++) {
        float4 t0 = q4r[k];
        qrA[4*k+0]=t0.x; qrA[4*k+1]=t0.y; qrA[4*k+2]=t0.z; qrA[4*k+3]=t0.w;
        float4 t1 = q4i[k];
        qiA[4*k+0]=t1.x; qiA[4*k+1]=t1.y; qiA[4*k+2]=t1.z; qiA[4*k+3]=t1.w;
    }
    v2 qx[kN], qy[kN], u[kN];
#pragma unroll
    for (int n = 0; n < kN; n++) {
        qx[n] = mkv2(qrA[n], qrA[n]);
        qy[n] = mkv2(-qiA[n], qiA[n]);
        u[n]  = mkv2(0.0f, 0.0f);
    }

    const float4* xp = (const float4*)(x + (size_t)row * kL + (size_t)c * kCH);
#pragma unroll 1
    for (int ii = 0; ii < kCH / 32; ii++) {      // 4 super-iterations of 32 steps
        float xs[32];
#pragma unroll
        for (int k = 0; k < 8; k++) {            // 8 back-to-back dwordx4 loads (128B/lane)
            float4 t = xp[ii * 8 + k];
            xs[4*k+0]=t.x; xs[4*k+1]=t.y; xs[4*k+2]=t.z; xs[4*k+3]=t.w;
        }
#pragma unroll
        for (int j = 0; j < 32; j++) {
            v2 xv = mkv2(xs[j], 0.0f);
#pragma unroll
            for (int n = 0; n < kN; n++) {
                v2 a = v2fma(qx[n], u[n], xv);
                u[n] = v2fma(qy[n], mkv2(u[n].y, u[n].x), a);
            }
        }
    }

    float4* Fp = (float4*)(F + (size_t)tid * (kN * 2));
#pragma unroll
    for (int n = 0; n < kN; n += 2)
        Fp[n >> 1] = make_float4(u[n].x, u[n].y, u[n + 1].x, u[n + 1].y);
}

// Pass 2: sequential combine over chunks per (b,d,n); write Hinit in place + h_out.
__global__ void pass2_kernel(const float* __restrict__ ws,
                             float* __restrict__ FH,
                             float* __restrict__ hout) {
    int i = blockIdx.x * 256 + threadIdx.x;      // (b*kD + d)*kN + n
    if (i >= kB * kD * kN) return;
    int n = i & 15;
    int row = i >> 4;                            // b*kD + d
    int d = row & (kD - 1);
    int dn = d * kN + n;
    float qr = ws[dn], qi = ws[kDN + dn], p = ws[4 * kDN + dn];
    // qC = q^kCH by repeated squaring (kCH = 128 = 2^7)
    float ar = qr, ai = qi;
#pragma unroll
    for (int k = 0; k < 7; k++) {
        float nr = ar * ar - ai * ai;
        float ni = 2.0f * ar * ai;
        ar = nr; ai = ni;
    }
    float Hr = 0.0f, Hi = 0.0f;
    float* base = FH + (size_t)row * kC * kN * 2;
#pragma unroll 1
    for (int c = 0; c < kC; c++) {
        size_t off = ((size_t)c * kN + n) * 2;
        float Fr = base[off], Fi = base[off + 1];
        base[off] = Hr; base[off + 1] = Hi;      // state entering chunk c
        float nHr = __builtin_fmaf(ar, Hr, __builtin_fmaf(-ai, Hi, Fr));
        float nHi = __builtin_fmaf(ar, Hi, __builtin_fmaf(ai, Hr, Fi));
        Hr = nHr; Hi = nHi;
    }
    hout[2 * i]     = p * Hr;                    // h = p * u
    hout[2 * i + 1] = p * Hi;
}

// Pass 3: rerun recurrence from correct init, emit y.
__global__ __launch_bounds__(256) void pass3_kernel(const float* __restrict__ x,
                                                    const float* __restrict__ ws,
                                                    const float* __restrict__ H,
                                                    const float* __restrict__ omega,
                                                    float* __restrict__ y) {
    int tid = blockIdx.x * 256 + threadIdx.x;    // (b*kD + d)*kC + c
    int c   = tid & (kC - 1);
    int row = tid >> 5;
    int d   = row & (kD - 1);

    const float4* q4r = (const float4*)(ws + (size_t)d * kN);
    const float4* q4i = (const float4*)(ws + kDN + (size_t)d * kN);
    const float4* g4r = (const float4*)(ws + 2 * kDN + (size_t)d * kN);
    const float4* g4i = (const float4*)(ws + 3 * kDN + (size_t)d * kN);
    float qrA[kN], qiA[kN], grA[kN], giA[kN];
#pragma unroll
    for (int k = 0; k < 4; k++) {
        float4 t0 = q4r[k];
        qrA[4*k+0]=t0.x; qrA[4*k+1]=t0.y; qrA[4*k+2]=t0.z; qrA[4*k+3]=t0.w;
        float4 t1 = q4i[k];
        qiA[4*k+0]=t1.x; qiA[4*k+1]=t1.y; qiA[4*k+2]=t1.z; qiA[4*k+3]=t1.w;
        float4 t2 = g4r[k];
        grA[4*k+0]=t2.x; grA[4*k+1]=t2.y; grA[4*k+2]=t2.z; grA[4*k+3]=t2.w;
        float4 t3 = g4i[k];
        giA[4*k+0]=t3.x; giA[4*k+1]=t3.y; giA[4*k+2]=t3.z; giA[4*k+3]=t3.w;
    }
    v2 qx[kN], qy[kN], g[kN], u[kN];
#pragma unroll
    for (int n = 0; n < kN; n++) {
        qx[n] = mkv2(qrA[n], qrA[n]);
        qy[n] = mkv2(-qiA[n], qiA[n]);
        g[n]  = mkv2(grA[n], giA[n]);
    }
    const float4* Hp = (const float4*)(H + (size_t)tid * (kN * 2));
#pragma unroll
    for (int k = 0; k < kN / 2; k++) {
        float4 h = Hp[k];
        u[2 * k]     = mkv2(h.x, h.y);
        u[2 * k + 1] = mkv2(h.z, h.w);
    }
    float om = omega[d];

    const float4* xp = (const float4*)(x + (size_t)row * kL + (size_t)c * kCH);
    float4*       yp = (float4*)(y + (size_t)row * kL + (size_t)c * kCH);
#pragma unroll 1
    for (int ii = 0; ii < kCH / 32; ii++) {      // 4 super-iterations of 32 steps
        float xs[32], ys[32];
#pragma unroll
        for (int k = 0; k < 8; k++) {            // 8 back-to-back dwordx4 loads (128B/lane)
            float4 t = xp[ii * 8 + k];
            xs[4*k+0]=t.x; xs[4*k+1]=t.y; xs[4*k+2]=t.z; xs[4*k+3]=t.w;
        }
#pragma unroll
        for (int j = 0; j < 32; j++) {
            v2 xv = mkv2(xs[j], 0.0f);
            v2 acc0 = mkv2(0.0f, 0.0f), acc1 = mkv2(0.0f, 0.0f);
            v2 acc2 = mkv2(0.0f, 0.0f), acc3 = mkv2(0.0f, 0.0f);
#pragma unroll
            for (int n = 0; n < kN; n += 4) {
                v2 a;
                a = v2fma(qx[n], u[n], xv);
                u[n] = v2fma(qy[n], mkv2(u[n].y, u[n].x), a);
                acc0 = v2fma(g[n], u[n], acc0);
                a = v2fma(qx[n+1], u[n+1], xv);
                u[n+1] = v2fma(qy[n+1], mkv2(u[n+1].y, u[n+1].x), a);
                acc1 = v2fma(g[n+1], u[n+1], acc1);
                a = v2fma(qx[n+2], u[n+2], xv);
                u[n+2] = v2fma(qy[n+2], mkv2(u[n+2].y, u[n+2].x), a);
                acc2 = v2fma(g[n+2], u[n+2], acc2);
                a = v2fma(qx[n+3], u[n+3], xv);
                u[n+3] = v2fma(qy[n+3], mkv2(u[n+3].y, u[n+3].x), a);
                acc3 = v2fma(g[n+3], u[n+3], acc3);
            }
            v2 s = (acc0 + acc1) + (acc2 + acc3);
            ys[j] = s.x + s.y + om * xs[j];
        }
#pragma unroll
        for (int k = 0; k < 8; k++)              // 8 back-to-back dwordx4 stores (128B/lane)
            yp[ii * 8 + k] = make_float4(ys[4*k+0], ys[4*k+1], ys[4*k+2], ys[4*k+3]);
    }
}

extern "C" void kernel_launch(void* const* d_in, const int* in_sizes, int n_in,
                              void* d_out, int out_size, void* d_ws, size_t ws_size,
                              hipStream_t stream) {
    const float* x     = (const float*)d_in[0];
    const float* alpha = (const float*)d_in[1];
    const float* delta = (const float*)d_in[2];
    const float* theta = (const float*)d_in[3];
    const float* gamma = (const float*)d_in[4];
    const float* omega = (const float*)d_in[5];
    float* y    = (float*)d_out;
    float* hout = y + (size_t)kB * kD * kL;      // (B,D,N,2) after y
    float* ws   = (float*)d_ws;
    float* F    = ws + 5 * (size_t)kDN;

    coeff_kernel<<<kDN / 256, 256, 0, stream>>>(alpha, delta, theta, gamma, ws);
    pass1_kernel<<<(kB * kD * kC) / 256, 256, 0, stream>>>(x, ws, F);
    pass2_kernel<<<(kB * kD * kN) / 256, 256, 0, stream>>>(ws, F, hout);
    pass3_kernel<<<(kB * kD * kC) / 256, 256, 0, stream>>>(x, ws, F, omega, y);
}